// Round 1
// baseline (128.160 us; speedup 1.0000x reference)
//
#include <hip/hip_runtime.h>
#include <hip/hip_bf16.h>

// Sizes
#define B_NODES 256
#define C_FEAT  64
#define Y_DIM   16
#define Z_PATH  23
#define E_ATTR  10
#define WXV     4096        // 16^3
#define K_REAL  368         // 16*23
#define K_PAD   384
#define M_DIM   16384       // 256*64
#define N_DIM   4096

typedef __attribute__((ext_vector_type(8))) short bf16x8;
typedef __attribute__((ext_vector_type(4))) float f32x4;

__device__ inline unsigned short f2bf(float x) {
    union { float f; unsigned u; } v; v.f = x;
    unsigned r = v.u + 0x7fffu + ((v.u >> 16) & 1u);   // RNE
    return (unsigned short)(r >> 16);
}

__device__ inline void gload_lds16(const void* g, void* l) {
    __builtin_amdgcn_global_load_lds(
        (const __attribute__((address_space(1))) void*)g,
        (__attribute__((address_space(3))) void*)l,
        16, 0, 0);
}

// ---------------- prep A: A[b*64+c][j] = z[b,c,j/23] * t[j%23, c], bf16, K padded to 384
__global__ __launch_bounds__(256) void prep_a(
    const float* __restrict__ W, const float* __restrict__ z,
    const float* __restrict__ attr, unsigned short* __restrict__ A)
{
    int b = blockIdx.x;
    int tid = threadIdx.x;
    __shared__ float t_lds[Z_PATH * C_FEAT];   // [k][c]
    __shared__ float z_lds[C_FEAT * Y_DIM];    // [c][i]
    __shared__ float a_lds[E_ATTR];

    if (tid < E_ATTR) a_lds[tid] = attr[b * E_ATTR + tid];
    {   // load z[b]: 1024 floats, float4 per thread
        const float4* zg = (const float4*)(z + (size_t)b * (C_FEAT * Y_DIM));
        ((float4*)z_lds)[tid] = zg[tid];
    }
    __syncthreads();
    for (int idx = tid; idx < Z_PATH * C_FEAT; idx += 256) {
        int k = idx >> 6;          // /64
        int c = idx & 63;
        float acc = 0.f;
        #pragma unroll
        for (int e = 0; e < E_ATTR; ++e)
            acc += a_lds[e] * W[(e * Z_PATH + k) * C_FEAT + c];
        t_lds[idx] = acc;
    }
    __syncthreads();
    unsigned short* Ab = A + (size_t)b * C_FEAT * K_PAD;
    for (int f = tid; f < C_FEAT * K_PAD; f += 256) {
        int c = f / K_PAD;
        int j = f - c * K_PAD;
        float v = 0.f;
        if (j < K_REAL) {
            int i = j / Z_PATH;
            int k = j - i * Z_PATH;
            v = z_lds[c * Y_DIM + i] * t_lds[k * C_FEAT + c];
        }
        Ab[f] = f2bf(v);
    }
}

// ---------------- prep U: bf16 cast + pad rows 368 -> 384. grid = 4096*96/256
__global__ __launch_bounds__(256) void prep_u(
    const float* __restrict__ U, unsigned short* __restrict__ Ub)
{
    int f = blockIdx.x * 256 + threadIdx.x;    // [0, 4096*96)
    int row = f / 96;
    int q = f - row * 96;
    int j = q * 4;
    unsigned short o[4] = {0, 0, 0, 0};
    if (j < K_REAL) {
        float4 v = *(const float4*)(U + (size_t)row * K_REAL + j);
        o[0] = f2bf(v.x); o[1] = f2bf(v.y); o[2] = f2bf(v.z); o[3] = f2bf(v.w);
    }
    unsigned short* dst = Ub + (size_t)row * K_PAD + j;
    dst[0] = o[0]; dst[1] = o[1]; dst[2] = o[2]; dst[3] = o[3];
}

// ---------------- GEMM: C[16384][4096] = A[16384][384] x Bt[4096][384]^T (bf16 -> f32)
__global__ __launch_bounds__(256) void gemm_kernel(
    const unsigned short* __restrict__ A,
    const unsigned short* __restrict__ Bt,
    float* __restrict__ C)
{
    __shared__ unsigned short sA[128 * 32];
    __shared__ unsigned short sB[128 * 32];

    int bid = blockIdx.x;
    int wg = (bid & 7) * 512 + (bid >> 3);     // XCD swizzle (4096 % 8 == 0, bijective)
    int tm = wg >> 5;                          // 128 row-tiles
    int tn = wg & 31;                          // 32 col-tiles
    int tid = threadIdx.x;
    int lane = tid & 63;
    int w = tid >> 6;
    int wm = w >> 1, wn = w & 1;

    f32x4 acc[4][4];
    #pragma unroll
    for (int p = 0; p < 4; ++p)
        #pragma unroll
        for (int q = 0; q < 4; ++q)
            acc[p][q] = (f32x4){0.f, 0.f, 0.f, 0.f};

    const char* gA = (const char*)A;
    const char* gB = (const char*)Bt;
    int rowA0 = tm * 128;
    int rowB0 = tn * 128;
    int ch0 = w * 2;
    int lrow = lane >> 2;            // 0..15 rows within chunk
    int lk16 = (lane & 3) * 16;      // byte offset within 64B row-slice
    int fr_row = lane & 15;
    int fr_k = (lane >> 4) * 8;      // element offset

    for (int kk = 0; kk < K_PAD / 32; ++kk) {
        #pragma unroll
        for (int s = 0; s < 2; ++s) {
            int ch = ch0 + s;
            int r = ch * 16 + lrow;
            gload_lds16(gA + (size_t)(rowA0 + r) * (K_PAD * 2) + kk * 64 + lk16,
                        (char*)sA + ch * 1024);
            gload_lds16(gB + (size_t)(rowB0 + r) * (K_PAD * 2) + kk * 64 + lk16,
                        (char*)sB + ch * 1024);
        }
        __syncthreads();
        bf16x8 af[4], bfr[4];
        #pragma unroll
        for (int fm = 0; fm < 4; ++fm)
            af[fm] = *(const bf16x8*)&sA[(wm * 64 + fm * 16 + fr_row) * 32 + fr_k];
        #pragma unroll
        for (int fn = 0; fn < 4; ++fn)
            bfr[fn] = *(const bf16x8*)&sB[(wn * 64 + fn * 16 + fr_row) * 32 + fr_k];
        #pragma unroll
        for (int fm = 0; fm < 4; ++fm)
            #pragma unroll
            for (int fn = 0; fn < 4; ++fn)
                acc[fm][fn] = __builtin_amdgcn_mfma_f32_16x16x32_bf16(
                    af[fm], bfr[fn], acc[fm][fn], 0, 0, 0);
        __syncthreads();
    }

    int r0 = tm * 128 + wm * 64 + (lane >> 4) * 4;
    int c0 = tn * 128 + wn * 64 + (lane & 15);
    #pragma unroll
    for (int fm = 0; fm < 4; ++fm)
        #pragma unroll
        for (int fn = 0; fn < 4; ++fn)
            #pragma unroll
            for (int reg = 0; reg < 4; ++reg)
                C[(size_t)(r0 + fm * 16 + reg) * N_DIM + (c0 + fn * 16)] = acc[fm][fn][reg];
}

// ---------------- fallback (ws too small): direct f32, correct but slow
__global__ __launch_bounds__(256) void fallback_kernel(
    const float* __restrict__ U, const float* __restrict__ W,
    const float* __restrict__ z, const float* __restrict__ attr,
    float* __restrict__ out)
{
    int bc = blockIdx.x;
    int b = bc >> 6, c = bc & 63;
    int tid = threadIdx.x;
    __shared__ float zt[K_REAL];
    for (int idx = tid; idx < K_REAL; idx += 256) {
        int i = idx / Z_PATH;
        int k = idx - i * Z_PATH;
        float t = 0.f;
        #pragma unroll
        for (int e = 0; e < E_ATTR; ++e)
            t += attr[b * E_ATTR + e] * W[(e * Z_PATH + k) * C_FEAT + c];
        zt[idx] = z[((size_t)b * C_FEAT + c) * Y_DIM + i] * t;
    }
    __syncthreads();
    for (int n = tid; n < WXV; n += 256) {
        const float* Ur = U + (size_t)n * K_REAL;
        float s = 0.f;
        for (int j = 0; j < K_REAL; ++j) s += Ur[j] * zt[j];
        out[(size_t)bc * WXV + n] = s;
    }
}

extern "C" void kernel_launch(void* const* d_in, const int* in_sizes, int n_in,
                              void* d_out, int out_size, void* d_ws, size_t ws_size,
                              hipStream_t stream)
{
    const float* U    = (const float*)d_in[0];
    const float* W    = (const float*)d_in[1];
    const float* z    = (const float*)d_in[2];
    const float* attr = (const float*)d_in[3];
    float* out = (float*)d_out;

    size_t needA = (size_t)M_DIM * K_PAD * sizeof(unsigned short);
    size_t needU = (size_t)N_DIM * K_PAD * sizeof(unsigned short);
    if (ws_size >= needA + needU) {
        unsigned short* Abf = (unsigned short*)d_ws;
        unsigned short* Ubf = Abf + (size_t)M_DIM * K_PAD;
        prep_a<<<B_NODES, 256, 0, stream>>>(W, z, attr, Abf);
        prep_u<<<(N_DIM * 96) / 256, 256, 0, stream>>>(U, Ubf);
        gemm_kernel<<<4096, 256, 0, stream>>>(Abf, Ubf, out);
    } else {
        fallback_kernel<<<M_DIM, 256, 0, stream>>>(U, W, z, attr, out);
    }
}

// Round 2
// 103.969 us; speedup vs baseline: 1.2327x; 1.2327x over previous
//
#include <hip/hip_runtime.h>
#include <hip/hip_bf16.h>

// Sizes
#define B_NODES 256
#define C_FEAT  64
#define Y_DIM   16
#define Z_PATH  23
#define E_ATTR  10
#define WXV     4096        // 16^3
#define K_REAL  368         // 16*23
#define K_PAD   384
#define M_DIM   16384       // 256*64
#define N_DIM   4096

typedef __attribute__((ext_vector_type(8))) short bf16x8;
typedef __attribute__((ext_vector_type(8))) unsigned short u16x8;
typedef __attribute__((ext_vector_type(4))) float f32x4;

__device__ inline unsigned short f2bf(float x) {
    union { float f; unsigned u; } v; v.f = x;
    unsigned r = v.u + 0x7fffu + ((v.u >> 16) & 1u);   // RNE
    return (unsigned short)(r >> 16);
}

__device__ inline void gload_lds16(const void* g, void* l) {
    __builtin_amdgcn_global_load_lds(
        (const __attribute__((address_space(1))) void*)g,
        (__attribute__((address_space(3))) void*)l,
        16, 0, 0);
}

// ---------------- fused prep: blocks [0,256) build A; blocks [256,1792) cast U
__global__ __launch_bounds__(256) void prep_combined(
    const float* __restrict__ U, const float* __restrict__ W,
    const float* __restrict__ z, const float* __restrict__ attr,
    unsigned short* __restrict__ A, unsigned short* __restrict__ Ub)
{
    int blk = blockIdx.x;
    int tid = threadIdx.x;
    if (blk < B_NODES) {
        // ---- prep A: A[b*64+c][j] = z[b,c,j/23] * t[j%23, c], bf16, K padded to 384
        int b = blk;
        __shared__ float t_lds[Z_PATH * C_FEAT];   // [k][c]
        __shared__ float z_lds[C_FEAT * Y_DIM];    // [c][i]
        __shared__ float a_lds[E_ATTR];
        if (tid < E_ATTR) a_lds[tid] = attr[b * E_ATTR + tid];
        ((float4*)z_lds)[tid] = ((const float4*)(z + (size_t)b * 1024))[tid];
        __syncthreads();
        for (int idx = tid; idx < Z_PATH * C_FEAT; idx += 256) {
            int k = idx >> 6;
            int c = idx & 63;
            float acc = 0.f;
            #pragma unroll
            for (int e = 0; e < E_ATTR; ++e)
                acc += a_lds[e] * W[(e * Z_PATH + k) * C_FEAT + c];
            t_lds[idx] = acc;
        }
        __syncthreads();
        unsigned short* Ab = A + (size_t)b * C_FEAT * K_PAD;
        // 64 c-rows x 48 groups of 8 shorts (16B); 3072 groups / 256 thr = 12 each
        for (int u = tid; u < C_FEAT * 48; u += 256) {
            int c = u / 48;
            int g = u - c * 48;
            int j0 = g * 8;
            u16x8 pack;
            #pragma unroll
            for (int jj = 0; jj < 8; ++jj) {
                int j = j0 + jj;
                float v = 0.f;
                if (j < K_REAL) {
                    int i = j / Z_PATH;
                    int k = j - i * Z_PATH;
                    v = z_lds[c * Y_DIM + i] * t_lds[k * C_FEAT + c];
                }
                pack[jj] = f2bf(v);
            }
            *(u16x8*)&Ab[c * K_PAD + j0] = pack;
        }
    } else {
        // ---- prep U: bf16 cast + pad rows 368 -> 384
        int f = (blk - B_NODES) * 256 + tid;       // [0, 4096*96)
        int row = f / 96;
        int q = f - row * 96;
        int j = q * 4;
        unsigned short o[4] = {0, 0, 0, 0};
        if (j < K_REAL) {
            float4 v = *(const float4*)(U + (size_t)row * K_REAL + j);
            o[0] = f2bf(v.x); o[1] = f2bf(v.y); o[2] = f2bf(v.z); o[3] = f2bf(v.w);
        }
        unsigned short* dst = Ub + (size_t)row * K_PAD + j;
        dst[0] = o[0]; dst[1] = o[1]; dst[2] = o[2]; dst[3] = o[3];
    }
}

// ---------------- GEMM: C[16384][4096] = A[16384][384] x Bt[4096][384]^T (bf16 -> f32)
// 128x128 tile, BK=32, double-buffered LDS, counted vmcnt (never drain mid-loop)
__global__ __launch_bounds__(256) void gemm_kernel(
    const unsigned short* __restrict__ A,
    const unsigned short* __restrict__ Bt,
    float* __restrict__ C)
{
    __shared__ unsigned short sA[2][128 * 32];
    __shared__ unsigned short sB[2][128 * 32];

    int bid = blockIdx.x;
    int wg = (bid & 7) * 512 + (bid >> 3);     // XCD swizzle (4096 % 8 == 0, bijective)
    int tm = wg >> 5;                          // 128 row-tiles
    int tn = wg & 31;                          // 32 col-tiles
    int tid = threadIdx.x;
    int lane = tid & 63;
    int w = tid >> 6;
    int wm = w >> 1, wn = w & 1;

    f32x4 acc[4][4];
    #pragma unroll
    for (int p = 0; p < 4; ++p)
        #pragma unroll
        for (int q = 0; q < 4; ++q)
            acc[p][q] = (f32x4){0.f, 0.f, 0.f, 0.f};

    const char* gA = (const char*)A + (size_t)(tm * 128) * (K_PAD * 2);
    const char* gB = (const char*)Bt + (size_t)(tn * 128) * (K_PAD * 2);
    int ch0 = w * 2;
    int lrow = lane >> 2;            // 0..15 rows within chunk
    int lk16 = (lane & 3) * 16;      // byte offset within 64B row-slice
    int fr_row = lane & 15;
    int fr_k = (lane >> 4) * 8;      // element offset

    // stage K-tile t into buffer buf: 4 x gload_lds16 per thread (2 A, 2 B)
    auto stage = [&](int t, int buf) {
        #pragma unroll
        for (int s = 0; s < 2; ++s) {
            int ch = ch0 + s;
            int r = ch * 16 + lrow;
            gload_lds16(gA + (size_t)r * (K_PAD * 2) + t * 64 + lk16,
                        (char*)&sA[buf][0] + ch * 1024);
            gload_lds16(gB + (size_t)r * (K_PAD * 2) + t * 64 + lk16,
                        (char*)&sB[buf][0] + ch * 1024);
        }
    };

    // prologue: prefetch tiles 0 and 1
    stage(0, 0);
    stage(1, 1);
    __builtin_amdgcn_sched_barrier(0);
    asm volatile("s_waitcnt vmcnt(4)" ::: "memory");   // tile 0 landed
    __builtin_amdgcn_sched_barrier(0);
    __builtin_amdgcn_s_barrier();

    #pragma unroll
    for (int t = 0; t < 12; ++t) {
        const int cur = t & 1;
        bf16x8 af[4], bfr[4];
        #pragma unroll
        for (int fm = 0; fm < 4; ++fm)
            af[fm] = *(const bf16x8*)&sA[cur][(wm * 64 + fm * 16 + fr_row) * 32 + fr_k];
        #pragma unroll
        for (int fn = 0; fn < 4; ++fn)
            bfr[fn] = *(const bf16x8*)&sB[cur][(wn * 64 + fn * 16 + fr_row) * 32 + fr_k];
        #pragma unroll
        for (int fm = 0; fm < 4; ++fm)
            #pragma unroll
            for (int fn = 0; fn < 4; ++fn)
                acc[fm][fn] = __builtin_amdgcn_mfma_f32_16x16x32_bf16(
                    af[fm], bfr[fn], acc[fm][fn], 0, 0, 0);
        if (t < 11) {
            __builtin_amdgcn_sched_barrier(0);
            __builtin_amdgcn_s_barrier();              // A: all waves done reading buf[cur]
            if (t < 10) stage(t + 2, cur);             // async overwrite of buf[cur]
            __builtin_amdgcn_sched_barrier(0);         // pin stage-issue BEFORE counted wait
            if (t < 10) { asm volatile("s_waitcnt vmcnt(4)" ::: "memory"); }
            else        { asm volatile("s_waitcnt vmcnt(0)" ::: "memory"); }
            __builtin_amdgcn_sched_barrier(0);
            __builtin_amdgcn_s_barrier();              // B: buf[t+1] ready for all
            __builtin_amdgcn_sched_barrier(0);         // keep next iter's ds_reads below
        }
    }

    int r0 = tm * 128 + wm * 64 + (lane >> 4) * 4;
    int c0 = tn * 128 + wn * 64 + (lane & 15);
    #pragma unroll
    for (int fm = 0; fm < 4; ++fm)
        #pragma unroll
        for (int fn = 0; fn < 4; ++fn)
            #pragma unroll
            for (int reg = 0; reg < 4; ++reg)
                __builtin_nontemporal_store(acc[fm][fn][reg],
                    &C[(size_t)(r0 + fm * 16 + reg) * N_DIM + (c0 + fn * 16)]);
}

// ---------------- fallback (ws too small): direct f32, correct but slow
__global__ __launch_bounds__(256) void fallback_kernel(
    const float* __restrict__ U, const float* __restrict__ W,
    const float* __restrict__ z, const float* __restrict__ attr,
    float* __restrict__ out)
{
    int bc = blockIdx.x;
    int b = bc >> 6, c = bc & 63;
    int tid = threadIdx.x;
    __shared__ float zt[K_REAL];
    for (int idx = tid; idx < K_REAL; idx += 256) {
        int i = idx / Z_PATH;
        int k = idx - i * Z_PATH;
        float t = 0.f;
        #pragma unroll
        for (int e = 0; e < E_ATTR; ++e)
            t += attr[b * E_ATTR + e] * W[(e * Z_PATH + k) * C_FEAT + c];
        zt[idx] = z[((size_t)b * C_FEAT + c) * Y_DIM + i] * t;
    }
    __syncthreads();
    for (int n = tid; n < WXV; n += 256) {
        const float* Ur = U + (size_t)n * K_REAL;
        float s = 0.f;
        for (int j = 0; j < K_REAL; ++j) s += Ur[j] * zt[j];
        out[(size_t)bc * WXV + n] = s;
    }
}

extern "C" void kernel_launch(void* const* d_in, const int* in_sizes, int n_in,
                              void* d_out, int out_size, void* d_ws, size_t ws_size,
                              hipStream_t stream)
{
    const float* U    = (const float*)d_in[0];
    const float* W    = (const float*)d_in[1];
    const float* z    = (const float*)d_in[2];
    const float* attr = (const float*)d_in[3];
    float* out = (float*)d_out;

    size_t needA = (size_t)M_DIM * K_PAD * sizeof(unsigned short);
    size_t needU = (size_t)N_DIM * K_PAD * sizeof(unsigned short);
    if (ws_size >= needA + needU) {
        unsigned short* Abf = (unsigned short*)d_ws;
        unsigned short* Ubf = Abf + (size_t)M_DIM * K_PAD;
        prep_combined<<<B_NODES + (N_DIM * 96) / 256, 256, 0, stream>>>(U, W, z, attr, Abf, Ubf);
        gemm_kernel<<<4096, 256, 0, stream>>>(Abf, Ubf, out);
    } else {
        fallback_kernel<<<M_DIM, 256, 0, stream>>>(U, W, z, attr, out);
    }
}